// Round 12
// baseline (116.434 us; speedup 1.0000x reference)
//
#include <hip/hip_runtime.h>

#define NEG_BIG (-3.0e38f)

// R9 math (bit-identical consumed values) restructured: the 32 correlation
// chunks run as a REAL loop (4 iters x 8-chunk body, #pragma unroll 1) with
// loop-carried register rings, instead of a fully-unrolled straight line.
// Rationale (R10/R11 post-mortem): in straight-line code the compiler
// re-schedules reads at its own (short) distance — source-level ring depth is
// meaningless; waves stall ~360cy per ds_read. The loop backedge forces the
// ring schedule: window ring P depth 8, read lead 7 (slot c+7 read at chunk c,
// first consumed 5 chunks ~300cy later); video ring Q depth 4, lead 3.
// Also shrinks I$ footprint ~11KB -> ~5KB (straight-line code is re-fetched
// per wave with zero reuse). Tail guards removed: over-reads (slots up to
// 2m+38 / video+34) stay inside the wave-private 2112B region, never consumed.
//
// One block = 8 waves (512 thr); each wave = 2 samples (one per 32-lane half).
// Lane m owns 8 lags sh = (248-8m)+q, q=0..7 (sh=255 dummy).
// Window W[t] = apad[8m+4c+t]; acc[q] += v[4c+e]*W[7+e-q].
// Per-half region = 528 floats (2112B == 64 mod 128 -> complementary
// bank-groups for the two halves).
//   apad slots 0..95: zeros[0,128) | raw audio [128,256) | zeros [256,384)
//   video floats [384,512) (slots 96..127), pad [512,528).
__global__ __launch_bounds__(512) void avsync_kernel(
    const float* __restrict__ video, const float* __restrict__ audio,
    const float* __restrict__ W1, const float* __restrict__ b1,
    const float* __restrict__ W2, const float* __restrict__ b2,
    float* __restrict__ out) {
  __shared__ float lds[8448];   // 8 waves * 2 halves * 528 floats

  const int tid  = threadIdx.x;
  const int wid  = tid >> 6;
  const int lane = tid & 63;
  const int half = lane >> 5;
  const int m    = lane & 31;
  const int b    = (int)blockIdx.x * 16 + wid * 2 + half;

  float* hbase = &lds[(wid * 2 + half) * 528];

  const float4 v4 = *reinterpret_cast<const float4*>(video + (size_t)b * 128 + 4 * m);
  const float4 a4 = *reinterpret_cast<const float4*>(audio + (size_t)b * 128 + 4 * m);

  // ---- stage raw data (wave-private region, no barrier needed) ----
  float4 z4; z4.x = z4.y = z4.z = z4.w = 0.0f;
  float4* sl = reinterpret_cast<float4*>(hbase);
  sl[m]      = z4;        // apad slots [0,32)   = zeros
  sl[64 + m] = z4;        // apad slots [64,96)  = zeros
  sl[32 + m] = a4;        // apad slots [32,64)  = raw audio
  sl[96 + m] = v4;        // video
  // ---- norms (per half) ----
  float pv = v4.x * v4.x + v4.y * v4.y + v4.z * v4.z + v4.w * v4.w;
  float pa = a4.x * a4.x + a4.y * a4.y + a4.z * a4.z + a4.w * a4.w;
#pragma unroll
  for (int off = 1; off < 32; off <<= 1) {
    pv += __shfl_xor(pv, off, 32);
    pa += __shfl_xor(pa, off, 32);
  }
  const float nv = sqrtf(pv);
  const float na = sqrtf(pa);
  const float iv = 1.0f / fmaxf(nv, 1e-12f);
  const float ia = 1.0f / fmaxf(na, 1e-12f);

  // ---- phase statistic on normalized difference ----
  const float d0 = v4.x * iv - a4.x * ia;
  const float d1 = v4.y * iv - a4.y * ia;
  const float d2 = v4.z * iv - a4.z * ia;
  const float d3 = v4.w * iv - a4.w * ia;
  float sc = __cosf(d0) + __cosf(d1) + __cosf(d2) + __cosf(d3);
  float ss = __sinf(d0) + __sinf(d1) + __sinf(d2) + __sinf(d3);
#pragma unroll
  for (int off = 1; off < 32; off <<= 1) {
    sc += __shfl_xor(sc, off, 32);
    ss += __shfl_xor(ss, off, 32);
  }

  // ---- corr-independent stats precompute ----
  const float s_norm = iv * ia;
  const float rv = nv / fmaxf(nv, 1e-12f);
  const float ra = na / fmaxf(na, 1e-12f);
  const float rvra = rv * ra;
  const float er = (rv * rv) / (ra * ra + 1e-6f);
  const float mc = sc * (1.0f / 128.0f), ms = ss * (1.0f / 128.0f);
  const float pc = sqrtf(mc * mc + ms * ms);

  // ---- main correlation: rolled loop, forced ring schedule ----
  const float4* wb = reinterpret_cast<const float4*>(hbase) + 2 * m;
  const float4* vb = reinterpret_cast<const float4*>(hbase) + 96;

  float acc0 = 0.f, acc1 = 0.f, acc2 = 0.f, acc3 = 0.f;
  float acc4 = 0.f, acc5 = 0.f, acc6 = 0.f, acc7 = 0.f;

  // P ring depth 8: at loop top of iter i (base c0=8i), P[k]=slot c0+k, k=0..6.
  // Body chunk k: A=P[k],B=P[k+1],C=P[k+2] (mod 8); read slot c0+k+7 -> P[(k+7)%8].
  // Q ring depth 4: Q[k%4]=video slot; body chunk k: VA=Q[k%4], read c0+k+3 -> Q[(k+3)%4].
  float4 P0 = wb[0], P1 = wb[1], P2 = wb[2], P3 = wb[3],
         P4 = wb[4], P5 = wb[5], P6 = wb[6], P7;
  float4 Q0 = vb[0], Q1 = vb[1], Q2 = vb[2], Q3;

#define CHUNK8(k, A, B, C, D, VA, VQ)                                          \
  do {                                                                         \
    (D)  = wb[(k) + 7];                                                        \
    (VQ) = vb[(k) + 3];                                                        \
    acc0 = fmaf((VA).x, (B).w, acc0); acc0 = fmaf((VA).y, (C).x, acc0);        \
    acc0 = fmaf((VA).z, (C).y, acc0); acc0 = fmaf((VA).w, (C).z, acc0);        \
    acc1 = fmaf((VA).x, (B).z, acc1); acc1 = fmaf((VA).y, (B).w, acc1);        \
    acc1 = fmaf((VA).z, (C).x, acc1); acc1 = fmaf((VA).w, (C).y, acc1);        \
    acc2 = fmaf((VA).x, (B).y, acc2); acc2 = fmaf((VA).y, (B).z, acc2);        \
    acc2 = fmaf((VA).z, (B).w, acc2); acc2 = fmaf((VA).w, (C).x, acc2);        \
    acc3 = fmaf((VA).x, (B).x, acc3); acc3 = fmaf((VA).y, (B).y, acc3);        \
    acc3 = fmaf((VA).z, (B).z, acc3); acc3 = fmaf((VA).w, (B).w, acc3);        \
    acc4 = fmaf((VA).x, (A).w, acc4); acc4 = fmaf((VA).y, (B).x, acc4);        \
    acc4 = fmaf((VA).z, (B).y, acc4); acc4 = fmaf((VA).w, (B).z, acc4);        \
    acc5 = fmaf((VA).x, (A).z, acc5); acc5 = fmaf((VA).y, (A).w, acc5);        \
    acc5 = fmaf((VA).z, (B).x, acc5); acc5 = fmaf((VA).w, (B).y, acc5);        \
    acc6 = fmaf((VA).x, (A).y, acc6); acc6 = fmaf((VA).y, (A).z, acc6);        \
    acc6 = fmaf((VA).z, (A).w, acc6); acc6 = fmaf((VA).w, (B).x, acc6);        \
    acc7 = fmaf((VA).x, (A).x, acc7); acc7 = fmaf((VA).y, (A).y, acc7);        \
    acc7 = fmaf((VA).z, (A).z, acc7); acc7 = fmaf((VA).w, (A).w, acc7);        \
  } while (0)

#pragma unroll 1
  for (int i = 0; i < 4; ++i) {
    CHUNK8(0, P0, P1, P2, P7, Q0, Q3);
    CHUNK8(1, P1, P2, P3, P0, Q1, Q0);
    CHUNK8(2, P2, P3, P4, P1, Q2, Q1);
    CHUNK8(3, P3, P4, P5, P2, Q3, Q2);
    CHUNK8(4, P4, P5, P6, P3, Q0, Q3);
    CHUNK8(5, P5, P6, P7, P4, Q1, Q0);
    CHUNK8(6, P6, P7, P0, P5, Q2, Q1);
    CHUNK8(7, P7, P0, P1, P6, Q3, Q2);
    wb += 8;
    vb += 8;
  }
#undef CHUNK8

  // ---- per-lane stats: 8 lags, sh = (248-8m)+q ascending in q ----
  const float accv[8] = {acc0, acc1, acc2, acc3, acc4, acc5, acc6, acc7};
  const int sh0 = 248 - 8 * m;
  float sum = 0.f, ssq = 0.f, mx = NEG_BIG;
  int mi = 0;
#pragma unroll
  for (int q = 0; q < 8; ++q) {
    const int sh = sh0 + q;
    const bool realLag = (sh < 255);
    const float cv = accv[q];
    const float cs = realLag ? cv : 0.f;
    sum += cs;
    ssq = fmaf(cs, cs, ssq);
    const float cm = realLag ? cv : NEG_BIG;
    if (cm > mx) { mx = cm; mi = sh; }
  }
  // cross-lane reduce over the 32-lane half (max with min-index tie-break)
#pragma unroll
  for (int off = 1; off < 32; off <<= 1) {
    const float ov = __shfl_xor(mx, off, 32);
    const int   oi = __shfl_xor(mi, off, 32);
    if (ov > mx || (ov == mx && oi < mi)) { mx = ov; mi = oi; }
    sum += __shfl_xor(sum, off, 32);
    ssq += __shfl_xor(ssq, off, 32);
  }

  // ---- finalize stats (corr_normalized = s_norm * corr_raw) ----
  const float delay = (float)mi - 127.0f;
  const float cstr = (mx * s_norm) / (rvra + 1e-6f);
  const float mean_r = sum * (1.0f / 255.0f);
  const float var_r  = fmaxf(ssq * (1.0f / 255.0f) - mean_r * mean_r, 0.0f);
  const float cstd = s_norm * sqrtf(var_r);
  const float cons = 1.0f / (1.0f + fabsf(delay));

  const float s0 = delay * 0.1f;
  const float s1 = cstr;
  const float s2 = cstd;
  const float s3 = er;
  const float s4 = pc;
  const float s5 = cons;

  // ---- MLP: lane m of each half computes output feature m ----
  float h[16];
#pragma unroll
  for (int k = 0; k < 16; ++k) {
    float acch = b1[k];
    acch = fmaf(s0, W1[0 * 16 + k], acch);
    acch = fmaf(s1, W1[1 * 16 + k], acch);
    acch = fmaf(s2, W1[2 * 16 + k], acch);
    acch = fmaf(s3, W1[3 * 16 + k], acch);
    acch = fmaf(s4, W1[4 * 16 + k], acch);
    acch = fmaf(s5, W1[5 * 16 + k], acch);
    h[k] = fmaxf(acch, 0.0f);
  }
  float o = b2[m];
#pragma unroll
  for (int k = 0; k < 16; ++k) o = fmaf(h[k], W2[k * 32 + m], o);
  out[(size_t)b * 32 + m] = o;
}

extern "C" void kernel_launch(void* const* d_in, const int* in_sizes, int n_in,
                              void* d_out, int out_size, void* d_ws, size_t ws_size,
                              hipStream_t stream) {
  const float* video = (const float*)d_in[0];
  const float* audio = (const float*)d_in[1];
  const float* W1 = (const float*)d_in[2];
  const float* b1 = (const float*)d_in[3];
  const float* W2 = (const float*)d_in[4];
  const float* b2 = (const float*)d_in[5];
  float* out = (float*)d_out;

  const int B = in_sizes[0] / 128;        // 65536 samples
  const int blocks = B / 16;              // 2 samples/wave * 8 waves/block
  avsync_kernel<<<blocks, 512, 0, stream>>>(video, audio, W1, b1, W2, b2, out);
}

// Round 14
// 74.657 us; speedup vs baseline: 1.5596x; 1.5596x over previous
//
#include <hip/hip_runtime.h>

#define NEG_BIG (-3.0e38f)

// R9 kernel (72.0us, best verified) with ONE change: the three SUM reductions
// (pv/pa, sc/ss, sum/ssq) switch from 5-step ds_swizzle butterflies (DS pipe,
// ~30-40cy serial latency each) to DPP v_add_f32_dpp chains (VALU pipe, ~4cy)
// + readlane broadcast. Removes ~24 DS ops and ~500cy serial latency per wave.
// The argmax (mx/mi) reduction KEEPS the exact shuffle butterfly -- tie-break
// semantics must not change. Sum-order changes only perturb smooth stats
// (norms/mean/var) at ulp level; delay/argmax path is bit-identical.
// R13 fix: dpp ctrl/row_mask must be LITERAL constants -> template parameters.
//
// One block = 8 waves (512 thr); each wave = 2 samples (one per 32-lane half).
// Lane m owns 8 lags sh = (248-8m)+q, q=0..7 (sh=255 dummy).
// Window W[t] = apad[8m+4c+t], slots 2m+c..2m+c+2; acc[q] += v[4c+e]*W[7+e-q].
// Per-half region = 528 floats (2112B == 64 mod 128 -> the two halves land on
// complementary LDS bank-groups; wave b128 = structural 8-phase minimum).
//   apad slots 0..95: zeros[0,128) | raw audio [128,256) | zeros [256,384)
//   video floats [384,512) (slots 96..127), pad [512,528).
template <int CTRL, int RMASK>
__device__ __forceinline__ float dppadd(float x) {
  int t = __builtin_amdgcn_update_dpp(0, __float_as_int(x), CTRL, RMASK, 0xf, false);
  return x + __int_as_float(t);
}

// 32-lane sum within each half of the wave; returns the half's total in all lanes.
__device__ __forceinline__ float halfsum(float x, bool hi) {
  x = dppadd<0x111, 0xf>(x);   // row_shr:1
  x = dppadd<0x112, 0xf>(x);   // row_shr:2
  x = dppadd<0x114, 0xf>(x);   // row_shr:4
  x = dppadd<0x118, 0xf>(x);   // row_shr:8  -> lane15/31/47/63 = 16-lane row sums
  x = dppadd<0x142, 0xa>(x);   // row_bcast:15 into rows 1,3 -> lane31/63 = half sums
  const float lo_s = __int_as_float(__builtin_amdgcn_readlane(__float_as_int(x), 31));
  const float hi_s = __int_as_float(__builtin_amdgcn_readlane(__float_as_int(x), 63));
  return hi ? hi_s : lo_s;
}

__global__ __launch_bounds__(512) void avsync_kernel(
    const float* __restrict__ video, const float* __restrict__ audio,
    const float* __restrict__ W1, const float* __restrict__ b1,
    const float* __restrict__ W2, const float* __restrict__ b2,
    float* __restrict__ out) {
  __shared__ float lds[8448];   // 8 waves * 2 halves * 528 floats

  const int tid  = threadIdx.x;
  const int wid  = tid >> 6;
  const int lane = tid & 63;
  const int half = lane >> 5;
  const int m    = lane & 31;
  const int b    = (int)blockIdx.x * 16 + wid * 2 + half;
  const bool hi  = (half != 0);

  float* hbase = &lds[(wid * 2 + half) * 528];

  const float4 v4 = *reinterpret_cast<const float4*>(video + (size_t)b * 128 + 4 * m);
  const float4 a4 = *reinterpret_cast<const float4*>(audio + (size_t)b * 128 + 4 * m);

  // ---- stage raw data (wave-private region, no barrier needed) ----
  float4 z4; z4.x = z4.y = z4.z = z4.w = 0.0f;
  float4* sl = reinterpret_cast<float4*>(hbase);
  sl[m]      = z4;        // apad slots [0,32)   = zeros
  sl[64 + m] = z4;        // apad slots [64,96)  = zeros
  sl[32 + m] = a4;        // apad slots [32,64)  = raw audio
  sl[96 + m] = v4;        // video

  // ---- norms (per half, DPP) ----
  float pv = v4.x * v4.x + v4.y * v4.y + v4.z * v4.z + v4.w * v4.w;
  float pa = a4.x * a4.x + a4.y * a4.y + a4.z * a4.z + a4.w * a4.w;
  pv = halfsum(pv, hi);
  pa = halfsum(pa, hi);
  const float nv = sqrtf(pv);
  const float na = sqrtf(pa);
  const float iv = 1.0f / fmaxf(nv, 1e-12f);
  const float ia = 1.0f / fmaxf(na, 1e-12f);

  // ---- phase statistic on normalized difference (DPP sums) ----
  const float d0 = v4.x * iv - a4.x * ia;
  const float d1 = v4.y * iv - a4.y * ia;
  const float d2 = v4.z * iv - a4.z * ia;
  const float d3 = v4.w * iv - a4.w * ia;
  float sc = __cosf(d0) + __cosf(d1) + __cosf(d2) + __cosf(d3);
  float ss = __sinf(d0) + __sinf(d1) + __sinf(d2) + __sinf(d3);
  sc = halfsum(sc, hi);
  ss = halfsum(ss, hi);

  // ---- corr-independent stats precompute ----
  const float s_norm = iv * ia;
  const float rv = nv / fmaxf(nv, 1e-12f);
  const float ra = na / fmaxf(na, 1e-12f);
  const float rvra = rv * ra;
  const float er = (rv * rv) / (ra * ra + 1e-6f);
  const float mc = sc * (1.0f / 128.0f), ms = ss * (1.0f / 128.0f);
  const float pc = sqrtf(mc * mc + ms * ms);

  // ---- main correlation: single stride-2 window, immediate offsets ----
  const float4* wbase = reinterpret_cast<const float4*>(hbase) + 2 * m;
  const float4* vbase = reinterpret_cast<const float4*>(hbase) + 96;

  float acc0 = 0.f, acc1 = 0.f, acc2 = 0.f, acc3 = 0.f;
  float acc4 = 0.f, acc5 = 0.f, acc6 = 0.f, acc7 = 0.f;

  float4 P0 = wbase[0], P1 = wbase[1], P2 = wbase[2], P3 = wbase[3], P4;
  float4 Q0 = vbase[0], Q1 = vbase[1], Q2;

  // chunk c: A=P[c%5], B=P[(c+1)%5], C=P[(c+2)%5], read wbase[c+4] -> P[(c+4)%5];
  //          VA=Q[c%3], read vbase[c+2] -> Q[(c+2)%3].  Reads only for c<30.
#define CHUNK(c, A, B, C, D, VA, VQ)                                           \
  do {                                                                         \
    if ((c) < 30) {                                                            \
      (D)  = wbase[(c) + 4];                                                   \
      (VQ) = vbase[(c) + 2];                                                   \
    }                                                                          \
    acc0 = fmaf((VA).x, (B).w, acc0); acc0 = fmaf((VA).y, (C).x, acc0);        \
    acc0 = fmaf((VA).z, (C).y, acc0); acc0 = fmaf((VA).w, (C).z, acc0);        \
    acc1 = fmaf((VA).x, (B).z, acc1); acc1 = fmaf((VA).y, (B).w, acc1);        \
    acc1 = fmaf((VA).z, (C).x, acc1); acc1 = fmaf((VA).w, (C).y, acc1);        \
    acc2 = fmaf((VA).x, (B).y, acc2); acc2 = fmaf((VA).y, (B).z, acc2);        \
    acc2 = fmaf((VA).z, (B).w, acc2); acc2 = fmaf((VA).w, (C).x, acc2);        \
    acc3 = fmaf((VA).x, (B).x, acc3); acc3 = fmaf((VA).y, (B).y, acc3);        \
    acc3 = fmaf((VA).z, (B).z, acc3); acc3 = fmaf((VA).w, (B).w, acc3);        \
    acc4 = fmaf((VA).x, (A).w, acc4); acc4 = fmaf((VA).y, (B).x, acc4);        \
    acc4 = fmaf((VA).z, (B).y, acc4); acc4 = fmaf((VA).w, (B).z, acc4);        \
    acc5 = fmaf((VA).x, (A).z, acc5); acc5 = fmaf((VA).y, (A).w, acc5);        \
    acc5 = fmaf((VA).z, (B).x, acc5); acc5 = fmaf((VA).w, (B).y, acc5);        \
    acc6 = fmaf((VA).x, (A).y, acc6); acc6 = fmaf((VA).y, (A).z, acc6);        \
    acc6 = fmaf((VA).z, (A).w, acc6); acc6 = fmaf((VA).w, (B).x, acc6);        \
    acc7 = fmaf((VA).x, (A).x, acc7); acc7 = fmaf((VA).y, (A).y, acc7);        \
    acc7 = fmaf((VA).z, (A).z, acc7); acc7 = fmaf((VA).w, (A).w, acc7);        \
  } while (0)

  CHUNK( 0, P0, P1, P2, P4, Q0, Q2);
  CHUNK( 1, P1, P2, P3, P0, Q1, Q0);
  CHUNK( 2, P2, P3, P4, P1, Q2, Q1);
  CHUNK( 3, P3, P4, P0, P2, Q0, Q2);
  CHUNK( 4, P4, P0, P1, P3, Q1, Q0);
  CHUNK( 5, P0, P1, P2, P4, Q2, Q1);
  CHUNK( 6, P1, P2, P3, P0, Q0, Q2);
  CHUNK( 7, P2, P3, P4, P1, Q1, Q0);
  CHUNK( 8, P3, P4, P0, P2, Q2, Q1);
  CHUNK( 9, P4, P0, P1, P3, Q0, Q2);
  CHUNK(10, P0, P1, P2, P4, Q1, Q0);
  CHUNK(11, P1, P2, P3, P0, Q2, Q1);
  CHUNK(12, P2, P3, P4, P1, Q0, Q2);
  CHUNK(13, P3, P4, P0, P2, Q1, Q0);
  CHUNK(14, P4, P0, P1, P3, Q2, Q1);
  CHUNK(15, P0, P1, P2, P4, Q0, Q2);
  CHUNK(16, P1, P2, P3, P0, Q1, Q0);
  CHUNK(17, P2, P3, P4, P1, Q2, Q1);
  CHUNK(18, P3, P4, P0, P2, Q0, Q2);
  CHUNK(19, P4, P0, P1, P3, Q1, Q0);
  CHUNK(20, P0, P1, P2, P4, Q2, Q1);
  CHUNK(21, P1, P2, P3, P0, Q0, Q2);
  CHUNK(22, P2, P3, P4, P1, Q1, Q0);
  CHUNK(23, P3, P4, P0, P2, Q2, Q1);
  CHUNK(24, P4, P0, P1, P3, Q0, Q2);
  CHUNK(25, P0, P1, P2, P4, Q1, Q0);
  CHUNK(26, P1, P2, P3, P0, Q2, Q1);
  CHUNK(27, P2, P3, P4, P1, Q0, Q2);
  CHUNK(28, P3, P4, P0, P2, Q1, Q0);
  CHUNK(29, P4, P0, P1, P3, Q2, Q1);
  CHUNK(30, P0, P1, P2, P4, Q0, Q2);
  CHUNK(31, P1, P2, P3, P0, Q1, Q0);
#undef CHUNK

  // ---- per-lane stats: 8 lags, sh = (248-8m)+q ascending in q ----
  const float accv[8] = {acc0, acc1, acc2, acc3, acc4, acc5, acc6, acc7};
  const int sh0 = 248 - 8 * m;
  float sum = 0.f, ssq = 0.f, mx = NEG_BIG;
  int mi = 0;
#pragma unroll
  for (int q = 0; q < 8; ++q) {
    const int sh = sh0 + q;
    const bool realLag = (sh < 255);
    const float cv = accv[q];
    const float cs = realLag ? cv : 0.f;
    sum += cs;
    ssq = fmaf(cs, cs, ssq);
    const float cm = realLag ? cv : NEG_BIG;
    if (cm > mx) { mx = cm; mi = sh; }
  }
  // sum/ssq via DPP (order-insensitive smooth stats)
  sum = halfsum(sum, hi);
  ssq = halfsum(ssq, hi);
  // argmax keeps the EXACT shuffle butterfly (min-index tie-break)
#pragma unroll
  for (int off = 1; off < 32; off <<= 1) {
    const float ov = __shfl_xor(mx, off, 32);
    const int   oi = __shfl_xor(mi, off, 32);
    if (ov > mx || (ov == mx && oi < mi)) { mx = ov; mi = oi; }
  }

  // ---- finalize stats (corr_normalized = s_norm * corr_raw) ----
  const float delay = (float)mi - 127.0f;
  const float cstr = (mx * s_norm) / (rvra + 1e-6f);
  const float mean_r = sum * (1.0f / 255.0f);
  const float var_r  = fmaxf(ssq * (1.0f / 255.0f) - mean_r * mean_r, 0.0f);
  const float cstd = s_norm * sqrtf(var_r);
  const float cons = 1.0f / (1.0f + fabsf(delay));

  const float s0 = delay * 0.1f;
  const float s1 = cstr;
  const float s2 = cstd;
  const float s3 = er;
  const float s4 = pc;
  const float s5 = cons;

  // ---- MLP: lane m of each half computes output feature m ----
  float h[16];
#pragma unroll
  for (int k = 0; k < 16; ++k) {
    float acch = b1[k];
    acch = fmaf(s0, W1[0 * 16 + k], acch);
    acch = fmaf(s1, W1[1 * 16 + k], acch);
    acch = fmaf(s2, W1[2 * 16 + k], acch);
    acch = fmaf(s3, W1[3 * 16 + k], acch);
    acch = fmaf(s4, W1[4 * 16 + k], acch);
    acch = fmaf(s5, W1[5 * 16 + k], acch);
    h[k] = fmaxf(acch, 0.0f);
  }
  float o = b2[m];
#pragma unroll
  for (int k = 0; k < 16; ++k) o = fmaf(h[k], W2[k * 32 + m], o);
  out[(size_t)b * 32 + m] = o;
}

extern "C" void kernel_launch(void* const* d_in, const int* in_sizes, int n_in,
                              void* d_out, int out_size, void* d_ws, size_t ws_size,
                              hipStream_t stream) {
  const float* video = (const float*)d_in[0];
  const float* audio = (const float*)d_in[1];
  const float* W1 = (const float*)d_in[2];
  const float* b1 = (const float*)d_in[3];
  const float* W2 = (const float*)d_in[4];
  const float* b2 = (const float*)d_in[5];
  float* out = (float*)d_out;

  const int B = in_sizes[0] / 128;        // 65536 samples
  const int blocks = B / 16;              // 2 samples/wave * 8 waves/block
  avsync_kernel<<<blocks, 512, 0, stream>>>(video, audio, W1, b1, W2, b2, out);
}

// Round 16
// 71.503 us; speedup vs baseline: 1.6284x; 1.0441x over previous
//
#include <hip/hip_runtime.h>

#define NEG_BIG (-3.0e38f)

// REVERT to the fastest verified kernel (R10, 71.654us, absmax 0.0039).
// R15 lesson: s_setprio graft BROKE correctness (absmax 5.78 — stale-LDS
// read from perturbed waitcnt/scheduling around the intrinsic boundary,
// rule-#18 hazard class). T5 is unsafe on this kernel; no semantics-free
// levers remain. This structure is the session's verified optimum:
// straight-line unrolled body, single stride-2 window w/ lane-stride -1 slot,
// +64B-staggered halves (complementary bank-groups), deep register rings.
//
// One block = 8 waves (512 thr); each wave = 2 samples (one per 32-lane half).
// Lane m owns 8 lags sh = (248-8m)+q, q=0..7 (sh=255 dummy).
// Window W[t] = apad[8m+4c+t]; acc[q] += v[4c+e]*W[7+e-q].
// Per-half region = 528 floats (2112B == 64 mod 128).
//   apad slots 0..95: zeros[0,128) | raw audio [128,256) | zeros [256,384)
//   video floats [384,512) (slots 96..127), pad [512,528).
__global__ __launch_bounds__(512) void avsync_kernel(
    const float* __restrict__ video, const float* __restrict__ audio,
    const float* __restrict__ W1, const float* __restrict__ b1,
    const float* __restrict__ W2, const float* __restrict__ b2,
    float* __restrict__ out) {
  __shared__ float lds[8448];   // 8 waves * 2 halves * 528 floats

  const int tid  = threadIdx.x;
  const int wid  = tid >> 6;
  const int lane = tid & 63;
  const int half = lane >> 5;
  const int m    = lane & 31;
  const int b    = (int)blockIdx.x * 16 + wid * 2 + half;

  float* hbase = &lds[(wid * 2 + half) * 528];

  const float4 v4 = *reinterpret_cast<const float4*>(video + (size_t)b * 128 + 4 * m);
  const float4 a4 = *reinterpret_cast<const float4*>(audio + (size_t)b * 128 + 4 * m);

  // ---- stage raw data (wave-private region, no barrier needed) ----
  float4 z4; z4.x = z4.y = z4.z = z4.w = 0.0f;
  float4* sl = reinterpret_cast<float4*>(hbase);
  sl[m]      = z4;        // apad slots [0,32)   = zeros
  sl[64 + m] = z4;        // apad slots [64,96)  = zeros
  sl[32 + m] = a4;        // apad slots [32,64)  = raw audio
  sl[96 + m] = v4;        // video
  // ---- norms (per half) ----
  float pv = v4.x * v4.x + v4.y * v4.y + v4.z * v4.z + v4.w * v4.w;
  float pa = a4.x * a4.x + a4.y * a4.y + a4.z * a4.z + a4.w * a4.w;
#pragma unroll
  for (int off = 1; off < 32; off <<= 1) {
    pv += __shfl_xor(pv, off, 32);
    pa += __shfl_xor(pa, off, 32);
  }
  const float nv = sqrtf(pv);
  const float na = sqrtf(pa);
  const float iv = 1.0f / fmaxf(nv, 1e-12f);
  const float ia = 1.0f / fmaxf(na, 1e-12f);

  // ---- phase statistic on normalized difference ----
  const float d0 = v4.x * iv - a4.x * ia;
  const float d1 = v4.y * iv - a4.y * ia;
  const float d2 = v4.z * iv - a4.z * ia;
  const float d3 = v4.w * iv - a4.w * ia;
  float sc = __cosf(d0) + __cosf(d1) + __cosf(d2) + __cosf(d3);
  float ss = __sinf(d0) + __sinf(d1) + __sinf(d2) + __sinf(d3);
#pragma unroll
  for (int off = 1; off < 32; off <<= 1) {
    sc += __shfl_xor(sc, off, 32);
    ss += __shfl_xor(ss, off, 32);
  }

  // ---- corr-independent stats precompute ----
  const float s_norm = iv * ia;
  const float rv = nv / fmaxf(nv, 1e-12f);
  const float ra = na / fmaxf(na, 1e-12f);
  const float rvra = rv * ra;
  const float er = (rv * rv) / (ra * ra + 1e-6f);
  const float mc = sc * (1.0f / 128.0f), ms = ss * (1.0f / 128.0f);
  const float pc = sqrtf(mc * mc + ms * ms);

  // ---- main correlation: single stride-2 window, immediate offsets ----
  const float4* wbase = reinterpret_cast<const float4*>(hbase) + 2 * m;
  const float4* vbase = reinterpret_cast<const float4*>(hbase) + 96;

  float acc0 = 0.f, acc1 = 0.f, acc2 = 0.f, acc3 = 0.f;
  float acc4 = 0.f, acc5 = 0.f, acc6 = 0.f, acc7 = 0.f;

  // P ring: 7-deep, P[s%7] holds window slot s; prefetch slot c+6 at chunk c.
  float4 P0 = wbase[0], P1 = wbase[1], P2 = wbase[2], P3 = wbase[3],
         P4 = wbase[4], P5 = wbase[5], P6;
  // Q ring: 6-deep, Q[s%6] holds video slot s; prefetch slot c+5 at chunk c.
  float4 Q0 = vbase[0], Q1 = vbase[1], Q2 = vbase[2], Q3 = vbase[3],
         Q4 = vbase[4], Q5;

  // chunk c: A=P[c%7], B=P[(c+1)%7], C=P[(c+2)%7], D=P[(c+6)%7] (prefetch tgt);
  //          VA=Q[c%6], VQ=Q[(c+5)%6] (prefetch tgt).
#define CHUNK(c, A, B, C, D, VA, VQ)                                           \
  do {                                                                         \
    if ((c) <= 27) (D)  = wbase[(c) + 6];                                      \
    if ((c) <= 26) (VQ) = vbase[(c) + 5];                                      \
    acc0 = fmaf((VA).x, (B).w, acc0); acc0 = fmaf((VA).y, (C).x, acc0);        \
    acc0 = fmaf((VA).z, (C).y, acc0); acc0 = fmaf((VA).w, (C).z, acc0);        \
    acc1 = fmaf((VA).x, (B).z, acc1); acc1 = fmaf((VA).y, (B).w, acc1);        \
    acc1 = fmaf((VA).z, (C).x, acc1); acc1 = fmaf((VA).w, (C).y, acc1);        \
    acc2 = fmaf((VA).x, (B).y, acc2); acc2 = fmaf((VA).y, (B).z, acc2);        \
    acc2 = fmaf((VA).z, (B).w, acc2); acc2 = fmaf((VA).w, (C).x, acc2);        \
    acc3 = fmaf((VA).x, (B).x, acc3); acc3 = fmaf((VA).y, (B).y, acc3);        \
    acc3 = fmaf((VA).z, (B).z, acc3); acc3 = fmaf((VA).w, (B).w, acc3);        \
    acc4 = fmaf((VA).x, (A).w, acc4); acc4 = fmaf((VA).y, (B).x, acc4);        \
    acc4 = fmaf((VA).z, (B).y, acc4); acc4 = fmaf((VA).w, (B).z, acc4);        \
    acc5 = fmaf((VA).x, (A).z, acc5); acc5 = fmaf((VA).y, (A).w, acc5);        \
    acc5 = fmaf((VA).z, (B).x, acc5); acc5 = fmaf((VA).w, (B).y, acc5);        \
    acc6 = fmaf((VA).x, (A).y, acc6); acc6 = fmaf((VA).y, (A).z, acc6);        \
    acc6 = fmaf((VA).z, (A).w, acc6); acc6 = fmaf((VA).w, (B).x, acc6);        \
    acc7 = fmaf((VA).x, (A).x, acc7); acc7 = fmaf((VA).y, (A).y, acc7);        \
    acc7 = fmaf((VA).z, (A).z, acc7); acc7 = fmaf((VA).w, (A).w, acc7);        \
  } while (0)

  CHUNK( 0, P0, P1, P2, P6, Q0, Q5);
  CHUNK( 1, P1, P2, P3, P0, Q1, Q0);
  CHUNK( 2, P2, P3, P4, P1, Q2, Q1);
  CHUNK( 3, P3, P4, P5, P2, Q3, Q2);
  CHUNK( 4, P4, P5, P6, P3, Q4, Q3);
  CHUNK( 5, P5, P6, P0, P4, Q5, Q4);
  CHUNK( 6, P6, P0, P1, P5, Q0, Q5);
  CHUNK( 7, P0, P1, P2, P6, Q1, Q0);
  CHUNK( 8, P1, P2, P3, P0, Q2, Q1);
  CHUNK( 9, P2, P3, P4, P1, Q3, Q2);
  CHUNK(10, P3, P4, P5, P2, Q4, Q3);
  CHUNK(11, P4, P5, P6, P3, Q5, Q4);
  CHUNK(12, P5, P6, P0, P4, Q0, Q5);
  CHUNK(13, P6, P0, P1, P5, Q1, Q0);
  CHUNK(14, P0, P1, P2, P6, Q2, Q1);
  CHUNK(15, P1, P2, P3, P0, Q3, Q2);
  CHUNK(16, P2, P3, P4, P1, Q4, Q3);
  CHUNK(17, P3, P4, P5, P2, Q5, Q4);
  CHUNK(18, P4, P5, P6, P3, Q0, Q5);
  CHUNK(19, P5, P6, P0, P4, Q1, Q0);
  CHUNK(20, P6, P0, P1, P5, Q2, Q1);
  CHUNK(21, P0, P1, P2, P6, Q3, Q2);
  CHUNK(22, P1, P2, P3, P0, Q4, Q3);
  CHUNK(23, P2, P3, P4, P1, Q5, Q4);
  CHUNK(24, P3, P4, P5, P2, Q0, Q5);
  CHUNK(25, P4, P5, P6, P3, Q1, Q0);
  CHUNK(26, P5, P6, P0, P4, Q2, Q1);
  CHUNK(27, P6, P0, P1, P5, Q3, Q2);
  CHUNK(28, P0, P1, P2, P6, Q4, Q3);
  CHUNK(29, P1, P2, P3, P0, Q5, Q4);
  CHUNK(30, P2, P3, P4, P1, Q0, Q5);
  CHUNK(31, P3, P4, P5, P2, Q1, Q0);
#undef CHUNK

  // ---- per-lane stats: 8 lags, sh = (248-8m)+q ascending in q ----
  const float accv[8] = {acc0, acc1, acc2, acc3, acc4, acc5, acc6, acc7};
  const int sh0 = 248 - 8 * m;
  float sum = 0.f, ssq = 0.f, mx = NEG_BIG;
  int mi = 0;
#pragma unroll
  for (int q = 0; q < 8; ++q) {
    const int sh = sh0 + q;
    const bool realLag = (sh < 255);
    const float cv = accv[q];
    const float cs = realLag ? cv : 0.f;
    sum += cs;
    ssq = fmaf(cs, cs, ssq);
    const float cm = realLag ? cv : NEG_BIG;
    if (cm > mx) { mx = cm; mi = sh; }
  }
  // cross-lane reduce over the 32-lane half (max with min-index tie-break)
#pragma unroll
  for (int off = 1; off < 32; off <<= 1) {
    const float ov = __shfl_xor(mx, off, 32);
    const int   oi = __shfl_xor(mi, off, 32);
    if (ov > mx || (ov == mx && oi < mi)) { mx = ov; mi = oi; }
    sum += __shfl_xor(sum, off, 32);
    ssq += __shfl_xor(ssq, off, 32);
  }

  // ---- finalize stats (corr_normalized = s_norm * corr_raw) ----
  const float delay = (float)mi - 127.0f;
  const float cstr = (mx * s_norm) / (rvra + 1e-6f);
  const float mean_r = sum * (1.0f / 255.0f);
  const float var_r  = fmaxf(ssq * (1.0f / 255.0f) - mean_r * mean_r, 0.0f);
  const float cstd = s_norm * sqrtf(var_r);
  const float cons = 1.0f / (1.0f + fabsf(delay));

  const float s0 = delay * 0.1f;
  const float s1 = cstr;
  const float s2 = cstd;
  const float s3 = er;
  const float s4 = pc;
  const float s5 = cons;

  // ---- MLP: lane m of each half computes output feature m ----
  float h[16];
#pragma unroll
  for (int k = 0; k < 16; ++k) {
    float acch = b1[k];
    acch = fmaf(s0, W1[0 * 16 + k], acch);
    acch = fmaf(s1, W1[1 * 16 + k], acch);
    acch = fmaf(s2, W1[2 * 16 + k], acch);
    acch = fmaf(s3, W1[3 * 16 + k], acch);
    acch = fmaf(s4, W1[4 * 16 + k], acch);
    acch = fmaf(s5, W1[5 * 16 + k], acch);
    h[k] = fmaxf(acch, 0.0f);
  }
  float o = b2[m];
#pragma unroll
  for (int k = 0; k < 16; ++k) o = fmaf(h[k], W2[k * 32 + m], o);
  out[(size_t)b * 32 + m] = o;
}

extern "C" void kernel_launch(void* const* d_in, const int* in_sizes, int n_in,
                              void* d_out, int out_size, void* d_ws, size_t ws_size,
                              hipStream_t stream) {
  const float* video = (const float*)d_in[0];
  const float* audio = (const float*)d_in[1];
  const float* W1 = (const float*)d_in[2];
  const float* b1 = (const float*)d_in[3];
  const float* W2 = (const float*)d_in[4];
  const float* b2 = (const float*)d_in[5];
  float* out = (float*)d_out;

  const int B = in_sizes[0] / 128;        // 65536 samples
  const int blocks = B / 16;              // 2 samples/wave * 8 waves/block
  avsync_kernel<<<blocks, 512, 0, stream>>>(video, audio, W1, b1, W2, b2, out);
}